// Round 1
// baseline (241.790 us; speedup 1.0000x reference)
//
#include <hip/hip_runtime.h>
#include <math.h>

#define NV   8
#define NC   32
#define ND   64
#define NH   64
#define NW   64
#define IMG  128

// out[c][d][h][w] = (1/8) * sum_v bilinear(x_rays[v][c], gx(v,h,w), gy(d))
// gx = (cos*xw - sin*yh)/120 ; gy = zd/120 ; align_corners=True, zeros padding.

__global__ __launch_bounds__(256) void backproj_kernel(
    const float* __restrict__ x_rays,   // [NV, NC, IMG, IMG]
    const float* __restrict__ angles,   // [NV]
    float* __restrict__ out)            // [NC, ND, NH, NW]
{
    const int w  = threadIdx.x & 63;        // lane-contiguous along W
    const int cg = threadIdx.x >> 6;        // channel group 0..3 (8 ch each)
    const int h  = blockIdx.x & 63;
    const int d  = blockIdx.x >> 6;

    const float step = 240.0f / 63.0f;

    // --- y side: depends only on d ---
    const float zd = -120.0f + d * step;
    const float gy = zd * (1.0f / 120.0f);
    const float yf = (gy + 1.0f) * 63.5f;
    const float y0f = floorf(yf);
    const float wy1 = yf - y0f;
    const float wy0 = 1.0f - wy1;
    const int iy0 = (int)y0f;
    const int iy1 = iy0 + 1;
    const float fy0 = (iy0 >= 0 && iy0 < IMG) ? 1.0f : 0.0f;
    const float fy1 = (iy1 >= 0 && iy1 < IMG) ? 1.0f : 0.0f;
    const int iy0c = min(max(iy0, 0), IMG - 1);
    const int iy1c = min(max(iy1, 0), IMG - 1);
    const int r0 = iy0c * IMG;
    const int r1 = iy1c * IMG;

    // --- world coords in the rotation plane ---
    const float xw = -120.0f + w * step;
    const float yh = -120.0f + h * step;

    float acc[8];
#pragma unroll
    for (int i = 0; i < 8; ++i) acc[i] = 0.0f;

#pragma unroll
    for (int v = 0; v < NV; ++v) {
        const float a = angles[v];
        float s, c;
        sincosf(a, &s, &c);
        const float u  = c * xw - s * yh;
        const float gx = u * (1.0f / 120.0f);
        const float xf = (gx + 1.0f) * 63.5f;
        const float x0f = floorf(xf);
        const float wx1 = xf - x0f;
        const float wx0 = 1.0f - wx1;
        const int ix0 = (int)x0f;
        const int ix1 = ix0 + 1;
        const float fx0 = (ix0 >= 0 && ix0 < IMG) ? 1.0f : 0.0f;
        const float fx1 = (ix1 >= 0 && ix1 < IMG) ? 1.0f : 0.0f;
        const int ix0c = min(max(ix0, 0), IMG - 1);
        const int ix1c = min(max(ix1, 0), IMG - 1);

        const float w00 = wx0 * wy0 * fx0 * fy0;
        const float w01 = wx1 * wy0 * fx1 * fy0;
        const float w10 = wx0 * wy1 * fx0 * fy1;
        const float w11 = wx1 * wy1 * fx1 * fy1;

        const float* img = x_rays + (size_t)v * NC * IMG * IMG
                                  + (size_t)(cg * 8) * IMG * IMG;
#pragma unroll
        for (int ci = 0; ci < 8; ++ci) {
            const float* p = img + (size_t)ci * IMG * IMG;
            const float v00 = p[r0 + ix0c];
            const float v01 = p[r0 + ix1c];
            const float v10 = p[r1 + ix0c];
            const float v11 = p[r1 + ix1c];
            acc[ci] += v00 * w00 + v01 * w01 + v10 * w10 + v11 * w11;
        }
    }

    // --- store: lanes contiguous in w -> coalesced ---
#pragma unroll
    for (int ci = 0; ci < 8; ++ci) {
        const int ch = cg * 8 + ci;
        out[(((size_t)ch * ND + d) * NH + h) * NW + w] = acc[ci] * 0.125f;
    }
}

extern "C" void kernel_launch(void* const* d_in, const int* in_sizes, int n_in,
                              void* d_out, int out_size, void* d_ws, size_t ws_size,
                              hipStream_t stream) {
    const float* x_rays = (const float*)d_in[0];  // [1,8,32,128,128]
    const float* angles = (const float*)d_in[1];  // [1,8]
    float* out = (float*)d_out;                   // [1,32,64,64,64]

    dim3 grid(ND * NH);   // 4096 blocks: blockIdx = d*64 + h
    dim3 block(256);      // 64 w-lanes x 4 channel-groups
    backproj_kernel<<<grid, block, 0, stream>>>(x_rays, angles, out);
}